// Round 9
// baseline (2385.018 us; speedup 1.0000x reference)
//
#include <hip/hip_runtime.h>
#include <cstddef>

#define NNODES 10000
#define NEDGES 256000
#define NGRAPH 32
#define NELEM  10
#define FF     64
#define LL     9
#define NBB    8
#define HIDN   16
#define RMAXF  5.0f
#define INV_AVG 0.0390625f   /* 1/25.6 exact */
#define PI_F   3.14159265358979f
#define ECAP   98304         /* compact-edge capacity; expected active ~74.7k */
#define LSTR   640000        /* l-major stride for agg/dagg/feats: [l][n][f] */

// ---------------- workspace layout (float elements), ~120.9 MB ----------------
constexpr size_t O_H0    = 0;           // 640000
constexpr size_t O_S1    = 640000;      // 640000
constexpr size_t O_AGG1  = 1280000;     // 5760000 (fwd agg1; reused as d_agg2 in bwd)
constexpr size_t O_AGG2  = 7040000;     // 5760000 (fwd agg2; reused as d_agg1 in bwd)
constexpr size_t O_F1    = 12800000;    // 5760000 feats1 [l][n][g]
constexpr size_t O_F2    = 18560000;    // 5760000 feats2 [l][n][g]
constexpr size_t O_C1    = 24320000;    // 640000
constexpr size_t O_C2    = 24960000;    // 640000
constexpr size_t O_DS1   = 25600000;    // 640000
constexpr size_t O_DINV  = 26240000;    // 640000 (unused after fusion)
constexpr size_t O_DH0C  = 26880000;    // 640000 (unused after fusion)
constexpr size_t O_CSH   = 27520000;    // ECAP*9
constexpr size_t O_CEF   = 28404736;    // ECAP*8
constexpr size_t O_CR    = 29191168;    // ECAP
constexpr size_t O_CVEC  = 29289472;    // ECAP*3
constexpr size_t O_DVEC  = 29584384;    // ECAP*3
constexpr size_t O_DPOS  = 29879296;    // 30000
constexpr size_t O_CSND  = 29909296;    // ECAP ints
constexpr size_t O_CRCV  = 30007600;    // ECAP ints
constexpr size_t O_HIST  = 30105904;    // 10000 ints
constexpr size_t O_CURS  = 30115904;    // 10001 ints
constexpr size_t O_CNT   = 30125905;    // 2 ints
constexpr size_t O_W4P1  = 30125920;    // 49152 (W4 padded: [j][f][12], fwd only)
constexpr size_t O_W4P2  = 30175072;    // 49152

__device__ __forceinline__ float siluf(float z){
  return z*(1.f/(1.f+__expf(-z)));
}
__device__ __forceinline__ float wred(float v){
#pragma unroll
  for(int o=32;o>0;o>>=1) v += __shfl_xor(v,o,64);
  return v;
}

// ---------------- W4 pre-pad: W4P[j*768 + f*12 + l] = W4[j*576 + f*9 + l] ----------------
__global__ __launch_bounds__(256) void k_w4prep(
    const float* __restrict__ W4a, const float* __restrict__ W4b,
    float* __restrict__ W4Pa, float* __restrict__ W4Pb){
  int o = blockIdx.x*256 + threadIdx.x;          // 0..98303
  int which = (o >= 49152) ? 1 : 0;
  int oo = o - which*49152;
  int l = oo % 12;
  int fj = oo / 12;
  int ff = fj & 63;
  int j  = fj >> 6;
  const float* src = which ? W4b : W4a;
  float v = (l < 9) ? src[j*576 + ff*9 + l] : 0.f;
  (which ? W4Pb : W4Pa)[oo] = v;
}

// ---------------- node embedding + e0 ----------------
__global__ __launch_bounds__(256) void k_embed(
    const float* __restrict__ attrs, const float* __restrict__ Wemb,
    const float* __restrict__ ae, const int* __restrict__ batch,
    float* __restrict__ h0, float* __restrict__ totE, float* __restrict__ nodeE){
  int t = blockIdx.x*256 + threadIdx.x;
  int n = t >> 6, f = t & 63;
  float acc = 0.f;
#pragma unroll
  for(int k=0;k<NELEM;k++) acc += attrs[n*NELEM+k]*Wemb[k*FF+f];
  h0[(size_t)n*FF+f] = acc;
  if(f==0){
    float e0 = 0.f;
#pragma unroll
    for(int k=0;k<NELEM;k++) e0 += attrs[n*NELEM+k]*ae[k];
    nodeE[n] = e0;
    atomicAdd(&totE[batch[n]], e0);
  }
}

// ---------------- edge sort: count / scan / scatter / pad ----------------
__global__ __launch_bounds__(256) void k_count(
    const float* __restrict__ pos, const float* __restrict__ shifts,
    const int* __restrict__ eidx, int* __restrict__ hist){
  int e = blockIdx.x*256 + threadIdx.x;
  int sn = eidx[e], rc = eidx[NEDGES + e];
  float vx = pos[rc*3+0]-pos[sn*3+0]+shifts[(size_t)e*3+0];
  float vy = pos[rc*3+1]-pos[sn*3+1]+shifts[(size_t)e*3+1];
  float vz = pos[rc*3+2]-pos[sn*3+2]+shifts[(size_t)e*3+2];
  float r2 = vx*vx+vy*vy+vz*vz+1e-12f;
  if(r2 < RMAXF*RMAXF) atomicAdd(&hist[rc], 1);
}

__global__ __launch_bounds__(1024) void k_scan(
    const int* __restrict__ hist, int* __restrict__ cursor, int* __restrict__ cnt){
  __shared__ int buf[1024];
  __shared__ int carryS;
  int t = threadIdx.x;
  if(t==0) carryS = 0;
  __syncthreads();
  for(int c=0;c<10;c++){
    int i = c*1024 + t;
    int v = (i<NNODES)? hist[i] : 0;
    buf[t]=v;
    __syncthreads();
    for(int off=1; off<1024; off<<=1){
      int x = (t>=off)? buf[t-off] : 0;
      __syncthreads();
      buf[t] += x;
      __syncthreads();
    }
    int incl = buf[t];
    int base = carryS;
    if(i<NNODES) cursor[i] = base + incl - v;
    __syncthreads();
    if(t==1023) carryS += buf[1023];
    __syncthreads();
  }
  if(t==0){
    int n = carryS;
    cnt[0] = n;
    cnt[1] = (n+31)&~31;
  }
}

__global__ __launch_bounds__(256) void k_scatter(
    const float* __restrict__ pos, const float* __restrict__ shifts, const int* __restrict__ eidx,
    int* __restrict__ cursor,
    float* __restrict__ csh, float* __restrict__ cef, float* __restrict__ cr,
    float* __restrict__ cvec, int* __restrict__ csnd, int* __restrict__ crcv){
  int e = blockIdx.x*256 + threadIdx.x;
  int sn = eidx[e], rc = eidx[NEDGES + e];
  float vx = pos[rc*3+0]-pos[sn*3+0]+shifts[(size_t)e*3+0];
  float vy = pos[rc*3+1]-pos[sn*3+1]+shifts[(size_t)e*3+1];
  float vz = pos[rc*3+2]-pos[sn*3+2]+shifts[(size_t)e*3+2];
  float r2 = vx*vx+vy*vy+vz*vz+1e-12f;
  if(r2 >= RMAXF*RMAXF) return;
  float r = sqrtf(r2);
  int i = atomicAdd(&cursor[rc], 1);
  csnd[i]=sn; crcv[i]=rc; cr[i]=r;
  cvec[(size_t)i*3+0]=vx; cvec[(size_t)i*3+1]=vy; cvec[(size_t)i*3+2]=vz;
  float inv = 1.f/r, x=vx*inv, y=vy*inv, z=vz*inv;
  const float s3=1.7320508f, s5=2.23606798f, s15=3.87298335f;
  float* sh = csh + (size_t)i*LL;
  sh[0]=1.f; sh[1]=s3*x; sh[2]=s3*y; sh[3]=s3*z; sh[4]=s15*x*y; sh[5]=s15*y*z;
  sh[6]=0.5f*s5*(3.f*z*z-1.f); sh[7]=s15*x*z; sh[8]=0.5f*s15*(x*x-y*y);
  float xr = r*(1.f/RMAXF);
  float x2=xr*xr, x4=x2*x2, x6=x4*x2, x7=x6*xr, x8=x7*xr;
  float env = 1.f - 28.f*x6 + 48.f*x7 - 21.f*x8;
  const float CB = 0.632455532f;
#pragma unroll
  for(int b=0;b<NBB;b++){
    float a = (b+1)*(PI_F/RMAXF);
    cef[(size_t)i*NBB+b] = CB*sinf(a*r)*inv*env;
  }
}

__global__ void k_pad(float* csh, float* cef, float* cr, float* cvec,
                      int* csnd, int* crcv, const int* cnt){
  int n = cnt[0];
  int nr = cnt[1];
  int i = n + threadIdx.x;
  if(i < nr){
    csnd[i]=0; crcv[i]=NNODES-1; cr[i]=1.f;
    cvec[(size_t)i*3+0]=0.f; cvec[(size_t)i*3+1]=0.f; cvec[(size_t)i*3+2]=1.f;
    for(int l=0;l<LL;l++) csh[(size_t)i*LL+l]=0.f;
    for(int b=0;b<NBB;b++) cef[(size_t)i*NBB+b]=0.f;
  }
}

// ---------------- fused edge forward: MLP -> tw (W4 from global W4P) -> segmented reduce ----
__global__ __launch_bounds__(256,2) void k_edge_fwd(
    const float* __restrict__ csh, const float* __restrict__ cef,
    const int* __restrict__ csnd, const int* __restrict__ crcv, const int* __restrict__ cnt,
    const float* __restrict__ src,
    const float* __restrict__ W1, const float* __restrict__ W2,
    const float* __restrict__ W3, const float* __restrict__ W4P,
    float* __restrict__ agg){
  const int cnt32 = cnt[1];
  if((int)(blockIdx.x*32) >= cnt32) return;
  __shared__ float W1s[NBB*FF];
  __shared__ float Wbuf[FF*65];        // W2 -> W3
  __shared__ float hA[32*FF], hB[32*FF];
  __shared__ float shs[32*LL], efs[32*NBB];
  __shared__ int   sndS[32], rcvS[32];
  const int t = threadIdx.x;
  const size_t e0 = (size_t)blockIdx.x*32;
  for(int i=t;i<NBB*FF;i+=256) W1s[i]=W1[i];
  for(int i4=t;i4<1024;i4+=256){
    int i=i4*4; const float4 v=*(const float4*)&W2[i];
    float* dst=&Wbuf[((i>>6)*65)+(i&63)];
    dst[0]=v.x; dst[1]=v.y; dst[2]=v.z; dst[3]=v.w;
  }
  for(int i=t;i<32*LL;i+=256) shs[i]=csh[e0*LL+i];
  for(int i=t;i<32*NBB;i+=256) efs[i]=cef[e0*NBB+i];
  if(t<32){ sndS[t]=csnd[e0+t]; rcvS[t]=crcv[e0+t]; }
  __syncthreads();
  const int w=t>>6, f=t&63;
  // L1: h1 -> hA   (rows wave-private)
#pragma unroll
  for(int i=0;i<8;i++){
    int e=w*8+i; float z=0.f;
#pragma unroll
    for(int b=0;b<NBB;b++) z += efs[e*NBB+b]*W1s[b*FF+f];
    hA[e*FF+f]=siluf(z);
  }
  // L2: h2 -> hB  (Wbuf = W2)
#pragma unroll
  for(int i=0;i<8;i++){
    int e=w*8+i; float z=0.f;
#pragma unroll
    for(int j4=0;j4<16;j4++){
      const float4 hv=*(const float4*)&hA[e*FF+j4*4];
      z += hv.x*Wbuf[(j4*4+0)*65+f];
      z += hv.y*Wbuf[(j4*4+1)*65+f];
      z += hv.z*Wbuf[(j4*4+2)*65+f];
      z += hv.w*Wbuf[(j4*4+3)*65+f];
    }
    hB[e*FF+f]=siluf(z);
  }
  __syncthreads();
  for(int i4=t;i4<1024;i4+=256){
    int i=i4*4; const float4 v=*(const float4*)&W3[i];
    float* dst=&Wbuf[((i>>6)*65)+(i&63)];
    dst[0]=v.x; dst[1]=v.y; dst[2]=v.z; dst[3]=v.w;
  }
  __syncthreads();
  // L3: h3 -> hA  (Wbuf = W3)
#pragma unroll
  for(int i=0;i<8;i++){
    int e=w*8+i; float z=0.f;
#pragma unroll
    for(int j4=0;j4<16;j4++){
      const float4 hv=*(const float4*)&hB[e*FF+j4*4];
      z += hv.x*Wbuf[(j4*4+0)*65+f];
      z += hv.y*Wbuf[(j4*4+1)*65+f];
      z += hv.z*Wbuf[(j4*4+2)*65+f];
      z += hv.w*Wbuf[(j4*4+3)*65+f];
    }
    hA[e*FF+f]=siluf(z);
  }
  // W4 pass: direct from global W4P [j][f][12] — 8 edges/wave amortize the stream
  float tw[8][9];
#pragma unroll
  for(int i=0;i<8;i++)
#pragma unroll
    for(int l=0;l<LL;l++) tw[i][l]=0.f;
  for(int jc=0;jc<16;jc++){
    float4 h4[8];
#pragma unroll
    for(int i=0;i<8;i++) h4[i]=*(const float4*)&hA[(w*8+i)*FF + jc*4];
#pragma unroll
    for(int j4=0;j4<4;j4++){
      const float* wp = W4P + (size_t)(jc*4+j4)*768 + f*12;
      const float4 wa=*(const float4*)wp;
      const float4 wb=*(const float4*)(wp+4);
      const float  w8=wp[8];
#pragma unroll
      for(int i=0;i<8;i++){
        const float h3=(j4==0)?h4[i].x:(j4==1)?h4[i].y:(j4==2)?h4[i].z:h4[i].w;
        tw[i][0]+=h3*wa.x; tw[i][1]+=h3*wa.y; tw[i][2]+=h3*wa.z; tw[i][3]+=h3*wa.w;
        tw[i][4]+=h3*wb.x; tw[i][5]+=h3*wb.y; tw[i][6]+=h3*wb.z; tw[i][7]+=h3*wb.w;
        tw[i][8]+=h3*w8;
      }
    }
  }
  // epilogue: per-l LDS run reduction into l-major agg [l][n][f]; msgL = hB (h2 dead)
  float sv[8];
#pragma unroll
  for(int i=0;i<8;i++) sv[i] = src[(size_t)sndS[w*8+i]*FF + f];
  const bool leftStraddle  = (e0>0) && (crcv[e0-1] == rcvS[0]);
  const bool rightStraddle = ((int)(e0+32) < cnt32) && (crcv[e0+32] == rcvS[31]);
  float* msgL = hB;
#pragma unroll
  for(int l=0;l<LL;l++){
#pragma unroll
    for(int i=0;i<8;i++){
      int e=w*8+i;
      msgL[e*FF+f] = sv[i]*shs[e*LL+l]*tw[i][l]*INV_AVG;
    }
    __syncthreads();
#pragma unroll
    for(int s0=0;s0<8;s0++){
      int s = w*8+s0;
      int rc = rcvS[s];
      bool head = (s==0) || (rcvS[s-1]!=rc);
      if(head){
        int L=1;
        while(s+L<32 && rcvS[s+L]==rc) L++;
        float sum=0.f;
        for(int k=0;k<L;k++) sum += msgL[(s+k)*FF+f];
        bool atom = (s==0 && leftStraddle) || (s+L==32 && rightStraddle);
        float* ap = &agg[(size_t)l*LSTR + (size_t)rc*FF + f];
        if(atom) atomicAdd(ap, sum); else *ap = sum;
      }
    }
    __syncthreads();
  }
}

// ---------------- k_lin2: feats[l][n][g] = sum_f agg[l][n][f]*Wlin[l][f][g] (+sc at l=0) ----
// Fresh low-pressure structure: 32 nodes/block, acc[8]/thread, partial unroll.
__global__ __launch_bounds__(256,2) void k_lin2(
    const float* __restrict__ agg, const float* __restrict__ Wlin,
    const float* __restrict__ src, const float* __restrict__ Wsc,
    float* __restrict__ feats){
  const int l    = blockIdx.y;
  const int base = blockIdx.x*32;
  __shared__ float Wl[FF*65];
  __shared__ float aS[32*FF];
  const int t=threadIdx.x, w=t>>6, g=t&63;
  for(int i=t;i<FF*FF;i+=256) Wl[(i>>6)*65+(i&63)] = Wlin[(size_t)l*FF*FF+i];
#pragma unroll
  for(int j=0;j<8;j++){
    int idx=t+j*256;
    int n = base + (idx>>6);
    aS[idx] = (n<NNODES)? agg[(size_t)l*LSTR + (size_t)n*FF + (idx&63)] : 0.f;
  }
  __syncthreads();
  float acc[8];
#pragma unroll
  for(int i=0;i<8;i++) acc[i]=0.f;
#pragma unroll 4
  for(int f4=0;f4<16;f4++){
    float w0=Wl[(f4*4+0)*65+g], w1=Wl[(f4*4+1)*65+g],
          w2=Wl[(f4*4+2)*65+g], w3=Wl[(f4*4+3)*65+g];
#pragma unroll
    for(int i=0;i<8;i++){
      const float4 v = *(const float4*)&aS[(w*8+i)*FF + f4*4];
      acc[i] += w0*v.x+w1*v.y+w2*v.z+w3*v.w;
    }
  }
  if(l==0){
    __syncthreads();
    for(int i=t;i<FF*FF;i+=256) Wl[(i>>6)*65+(i&63)] = Wsc[i];
#pragma unroll
    for(int j=0;j<8;j++){
      int idx=t+j*256;
      int n = base + (idx>>6);
      aS[idx] = (n<NNODES)? src[(size_t)n*FF + (idx&63)] : 0.f;
    }
    __syncthreads();
#pragma unroll 4
    for(int f4=0;f4<16;f4++){
      float w0=Wl[(f4*4+0)*65+g], w1=Wl[(f4*4+1)*65+g],
            w2=Wl[(f4*4+2)*65+g], w3=Wl[(f4*4+3)*65+g];
#pragma unroll
      for(int i=0;i<8;i++){
        const float4 v = *(const float4*)&aS[(w*8+i)*FF + f4*4];
        acc[i] += w0*v.x+w1*v.y+w2*v.z+w3*v.w;
      }
    }
  }
#pragma unroll
  for(int i=0;i<8;i++){
    int n = base + w*8 + i;
    if(n<NNODES) feats[(size_t)l*LSTR + (size_t)n*FF + g] = acc[i];
  }
}

// ---------------- k_prod: inv, c, h, readout energies ----------------
template<int LAYER>
__global__ __launch_bounds__(256,2) void k_prod(
    const float* __restrict__ feats, const int* __restrict__ batch,
    const float* __restrict__ Wpr,
    const float* __restrict__ wread, const float* __restrict__ Wr1, const float* __restrict__ wr2,
    float* __restrict__ cbuf, float* __restrict__ s1out,
    float* __restrict__ nfeats, float* __restrict__ nodeE, float* __restrict__ totE){
  __shared__ float Wprs[FF*65];
  __shared__ float Wr1s[FF*HIDN];
  __shared__ float ivS[4][FF];
  const int t=threadIdx.x, w=t>>6, g=t&63;
  for(int i=t;i<FF*FF;i+=256) Wprs[(i>>6)*65+(i&63)]=Wpr[i];
  if(LAYER==2) for(int i=t;i<FF*HIDN;i+=256) Wr1s[i]=Wr1[i];
  __syncthreads();
  for(int k=0;k<2;k++){
    int n = blockIdx.x*8 + k*4 + w;
    if(n>=NNODES) continue;   // wave-uniform; no block barriers below
    float fr[9]; float iv=0.f;
#pragma unroll
    for(int l=0;l<LL;l++){ fr[l]=feats[(size_t)l*LSTR + (size_t)n*FF + g]; iv+=fr[l]*fr[l]; }
    ivS[w][g]=iv;
    float c=1.f;
#pragma unroll
    for(int gg=0;gg<FF;gg++) c += ivS[w][gg]*Wprs[gg*65+g];
    cbuf[(size_t)n*FF+g]=c;
    float* nf = nfeats + (size_t)n*(2*FF*LL) + (LAYER==2?FF*LL:0) + g*LL;
#pragma unroll
    for(int l=0;l<LL;l++) nf[l]=fr[l]*c;
    float s0 = fr[0]*c;
    float epart;
    if(LAYER==1){
      s1out[(size_t)n*FF+g]=s0;
      epart = s0*wread[g];
    } else {
      ivS[w][g]=s0;
      epart=0.f;
      if(g<HIDN){
        float tt=0.f;
#pragma unroll
        for(int gg=0;gg<FF;gg++) tt += ivS[w][gg]*Wr1s[gg*HIDN+g];
        epart = siluf(tt)*wr2[g];
      }
    }
    float es = wred(epart);
    if(g==0){ nodeE[n]+=es; atomicAdd(&totE[batch[n]], es); }
  }
}

// ---------------- k_node_bwd: fused bwd_prep + lin_bwd (dinv/dh0c stay in LDS) -------------
template<int LAYER>
__global__ __launch_bounds__(256,2) void k_node_bwd(
    const float* __restrict__ feats, const float* __restrict__ cbuf,
    const float* __restrict__ Wpr, const float* __restrict__ Wsc,
    const float* __restrict__ Wr1, const float* __restrict__ wr2,
    const float* __restrict__ wread, const float* __restrict__ ds1in,
    const float* __restrict__ Wlin,
    float* __restrict__ ds1out, float* __restrict__ dagg){
  __shared__ float WbufA[FF*65];                      // Wpr (phase A) -> Wlin[l] (phase B)
  __shared__ float WbufB[(LAYER==2)?FF*65:1];         // Wsc (L2 only)
  __shared__ float poolA[2048];                       // Wr1s[0..1023]+Wr1T[1024..2047] -> fS
  __shared__ float dinvS[32*FF];
  __shared__ float dh0cS[32*FF];
  __shared__ float rowS[4][FF];
  __shared__ float dtS[4][HIDN];
  const int t=threadIdx.x, w=t>>6, g=t&63;
  const int base = blockIdx.x*32;
  for(int i=t;i<FF*FF;i+=256) WbufA[(i>>6)*65+(i&63)]=Wpr[i];
  if(LAYER==2){
    for(int i=t;i<FF*FF;i+=256) WbufB[(i>>6)*65+(i&63)]=Wsc[i];
    for(int i=t;i<FF*HIDN;i+=256){
      poolA[i]=Wr1[i];                                // Wr1s [f][h]
      poolA[1024 + (i&15)*FF + (i>>4)]=Wr1[i];        // Wr1T [h][f]
    }
  }
  __syncthreads();
  // ---- phase A: dinv, dh0c (to LDS), ds1out (L2, global) ----
  for(int k=0;k<8;k++){
    int ni = k*4+w;
    int n  = base + ni;
    if(n>=NNODES) continue;                           // wave-uniform
    float f0 = feats[(size_t)n*FF+g];                 // l=0 plane
    float c  = cbuf[(size_t)n*FF+g];
    float dh0;
    if(LAYER==2){
      rowS[w][g] = f0*c;                              // s2 row
      if(g<HIDN){
        float tt=0.f;
#pragma unroll
        for(int gg=0;gg<FF;gg++) tt += rowS[w][gg]*poolA[gg*HIDN+g];
        float sg = 1.f/(1.f+__expf(-tt));
        dtS[w][g] = sg*(1.f + tt*(1.f-sg))*wr2[g];
      }
      dh0=0.f;
#pragma unroll
      for(int h=0;h<HIDN;h++) dh0 += dtS[w][h]*poolA[1024 + h*FF + g];
    } else {
      dh0 = wread[g] + ds1in[(size_t)n*FF+g];
    }
    rowS[w][g] = dh0*f0;                              // dc
    float dinv=0.f;
#pragma unroll
    for(int gg=0;gg<FF;gg++) dinv += rowS[w][gg]*WbufA[g*65+gg];
    dinvS[ni*FF+g]=dinv;
    dh0cS[ni*FF+g]=dh0*c;
    if(LAYER==2){
      rowS[w][g] = 2.f*dinv*f0 + dh0*c;               // df0
      float ds=0.f;
#pragma unroll
      for(int gg=0;gg<FF;gg++) ds += rowS[w][gg]*WbufB[g*65+gg];
      ds1out[(size_t)n*FF+g]=ds;
    }
  }
  __syncthreads();
  // ---- phase B: per-l GEMM  dagg[l][n][f] = sum_g df[n][g]*Wlin[l][f][g] ----
  float* fS = poolA;                                  // 2048 floats, reused
  for(int l=0;l<LL;l++){
    for(int i=t;i<FF*FF;i+=256) WbufA[(i>>6)*65+(i&63)]=Wlin[(size_t)l*FF*FF+i];
#pragma unroll
    for(int j=0;j<8;j++){
      int idx=t+j*256;
      int n = base + (idx>>6);
      float v=0.f;
      if(n<NNODES){
        float ft = feats[(size_t)l*LSTR+(size_t)n*FF+(idx&63)];
        v = 2.f*dinvS[idx]*ft;
        if(l==0) v += dh0cS[idx];
      }
      fS[idx]=v;
    }
    __syncthreads();
    float acc[8];
#pragma unroll
    for(int i=0;i<8;i++) acc[i]=0.f;
#pragma unroll 4
    for(int f4=0;f4<16;f4++){
      float w0=WbufA[g*65+f4*4+0], w1=WbufA[g*65+f4*4+1],
            w2=WbufA[g*65+f4*4+2], w3=WbufA[g*65+f4*4+3];
#pragma unroll
      for(int i=0;i<8;i++){
        const float4 v = *(const float4*)&fS[(w*8+i)*FF + f4*4];
        acc[i] += w0*v.x+w1*v.y+w2*v.z+w3*v.w;
      }
    }
#pragma unroll
    for(int i=0;i<8;i++){
      int n = base + w*8 + i;
      if(n<NNODES) dagg[(size_t)l*LSTR + (size_t)n*FF + g] = acc[i];
    }
    __syncthreads();
  }
}

// ---------------- fused edge backward: 2 edges/wave; LDS diet -> 4 blocks/CU ----------------
// W4 chunk staged INSIDE Wbuf[0..2303] (W3 restaged after the pass); redW aliased onto
// dead hP (wave0), hQ (wave1), Wbuf[2304..3327] (waves 2,3). LDS ~27.5KB; VGPR (<=128)
// now binds occupancy at 4 blocks/CU (2x round-8's 2 blocks).
template<int LAYER>
__global__ __launch_bounds__(256,2) void k_edge_bwd(
    const float* __restrict__ csh, const float* __restrict__ cef,
    const float* __restrict__ cr, const float* __restrict__ cvec,
    const int* __restrict__ csnd, const int* __restrict__ crcv, const int* __restrict__ cnt,
    const float* __restrict__ src,
    const float* __restrict__ W1, const float* __restrict__ W2,
    const float* __restrict__ W3, const float* __restrict__ W4,
    const float* __restrict__ dagg,
    float* __restrict__ ds1,
    float* __restrict__ dvec,
    float* __restrict__ dpos){
  if((int)(blockIdx.x*8) >= cnt[1]) return;
  __shared__ __align__(16) float W1s[NBB*FF];   // 2KB
  __shared__ __align__(16) float Wbuf[FF*65];   // W2 -> W3 -> {W4 chunk | redW w2,w3} -> W3 -> W2
  __shared__ __align__(16) float hP[8*FF];      // h1; redW wave0 during W4 pass
  __shared__ __align__(16) float hQ[8*FF];      // h2; redW wave1; dz3; dz2
  __shared__ __align__(16) float hR[8*FF];      // h3
  __shared__ float shs[8*LL], efs[8*NBB];
  __shared__ float dh3S[4*2*64];                // 2KB per-wave dh3 [w][i][j]
  __shared__ int sndS[8], rcvS[8];
  const int t=threadIdx.x, w=t>>6, f=t&63;
  const size_t e0=(size_t)blockIdx.x*8;
  const float4* W4v=(const float4*)W4;
  for(int i=t;i<NBB*FF;i+=256) W1s[i]=W1[i];
  for(int i4=t;i4<1024;i4+=256){
    int i=i4*4; const float4 v=*(const float4*)&W2[i];
    float* dst=&Wbuf[((i>>6)*65)+(i&63)];
    dst[0]=v.x; dst[1]=v.y; dst[2]=v.z; dst[3]=v.w;
  }
  if(t<8*LL)  shs[t]=csh[e0*LL+t];
  if(t<8*NBB) efs[t]=cef[e0*NBB+t];
  if(t<8){ sndS[t]=csnd[e0+t]; rcvS[t]=crcv[e0+t]; }
  __syncthreads();
  // early long-latency loads
  float sv[2], dtw[2][9];
  float z1r[2], z2r[2], z3r[2];
#pragma unroll
  for(int i=0;i<2;i++) sv[i]=src[(size_t)sndS[w*2+i]*FF+f];
#pragma unroll
  for(int i=0;i<2;i++){
    int le=w*2+i; int rc=rcvS[le];
#pragma unroll
    for(int l=0;l<LL;l++){
      float dm0=dagg[(size_t)l*LSTR+(size_t)rc*FF+f]*INV_AVG;
      dtw[i][l]=dm0*sv[i]*shs[le*LL+l];
    }
  }
  // MLP forward recompute; z kept in registers for the chain
#pragma unroll
  for(int i=0;i<2;i++){
    int le=w*2+i; float z=0.f;
#pragma unroll
    for(int b=0;b<NBB;b++) z += efs[le*NBB+b]*W1s[b*FF+f];
    z1r[i]=z; hP[le*FF+f]=siluf(z);
  }
#pragma unroll
  for(int i=0;i<2;i++){
    int le=w*2+i; float z=0.f;
#pragma unroll
    for(int j4=0;j4<16;j4++){
      const float4 hv=*(const float4*)&hP[le*FF+j4*4];
      z += hv.x*Wbuf[(j4*4+0)*65+f];
      z += hv.y*Wbuf[(j4*4+1)*65+f];
      z += hv.z*Wbuf[(j4*4+2)*65+f];
      z += hv.w*Wbuf[(j4*4+3)*65+f];
    }
    z2r[i]=z; hQ[le*FF+f]=siluf(z);
  }
  __syncthreads();
  for(int i4=t;i4<1024;i4+=256){
    int i=i4*4; const float4 v=*(const float4*)&W3[i];
    float* dst=&Wbuf[((i>>6)*65)+(i&63)];
    dst[0]=v.x; dst[1]=v.y; dst[2]=v.z; dst[3]=v.w;
  }
  __syncthreads();
#pragma unroll
  for(int i=0;i<2;i++){
    int le=w*2+i; float z=0.f;
#pragma unroll
    for(int j4=0;j4<16;j4++){
      const float4 hv=*(const float4*)&hQ[le*FF+j4*4];
      z += hv.x*Wbuf[(j4*4+0)*65+f];
      z += hv.y*Wbuf[(j4*4+1)*65+f];
      z += hv.z*Wbuf[(j4*4+2)*65+f];
      z += hv.w*Wbuf[(j4*4+3)*65+f];
    }
    z3r[i]=z; hR[le*FF+f]=siluf(z);
  }
  __syncthreads();   // all waves done with Wbuf(W3)+hP+hQ before W4 pass scribbles them
  // W4 pass: chunk jc staged into Wbuf[0..2303]; redW in dead LDS; 2 barriers/chunk
  float tw[2][9];
#pragma unroll
  for(int i=0;i<2;i++)
#pragma unroll
    for(int l=0;l<LL;l++) tw[i][l]=0.f;
  float* redW = (w==0)? hP : (w==1)? hQ : &Wbuf[2304 + (w-2)*512];
  const int row=f>>3, seg=f&7;
  for(int jc=0;jc<16;jc++){
    for(int d4=t; d4<576; d4+=256) ((float4*)Wbuf)[d4] = W4v[jc*576 + d4];
    __syncthreads();
    float4 h3v[2];
    h3v[0]=*(const float4*)&hR[(w*2+0)*FF + jc*4];
    h3v[1]=*(const float4*)&hR[(w*2+1)*FF + jc*4];
    float p[4][2];
#pragma unroll
    for(int j4=0;j4<4;j4++){
      const float* wp = Wbuf + j4*576 + f*9;
      const float w0=wp[0], w1=wp[1], w2=wp[2], w3=wp[3], w4_=wp[4],
                  w5=wp[5], w6=wp[6], w7=wp[7], w8=wp[8];
#pragma unroll
      for(int i=0;i<2;i++){
        const float h3=(j4==0)?h3v[i].x:(j4==1)?h3v[i].y:(j4==2)?h3v[i].z:h3v[i].w;
        tw[i][0]+=h3*w0; tw[i][1]+=h3*w1; tw[i][2]+=h3*w2; tw[i][3]+=h3*w3;
        tw[i][4]+=h3*w4_; tw[i][5]+=h3*w5; tw[i][6]+=h3*w6; tw[i][7]+=h3*w7;
        tw[i][8]+=h3*w8;
        float pp=0.f;
        pp+=dtw[i][0]*w0; pp+=dtw[i][1]*w1; pp+=dtw[i][2]*w2; pp+=dtw[i][3]*w3;
        pp+=dtw[i][4]*w4_; pp+=dtw[i][5]*w5; pp+=dtw[i][6]*w6; pp+=dtw[i][7]*w7;
        pp+=dtw[i][8]*w8;
        p[j4][i]=pp;
      }
    }
    // per-wave transpose-reduce (8 rows, XOR swizzle (r*9)&63 — verified round 2)
#pragma unroll
    for(int j4=0;j4<4;j4++)
#pragma unroll
      for(int i=0;i<2;i++){
        int r=j4*2+i;
        redW[r*64 + (f ^ ((r*9)&63))] = p[j4][i];
      }
    {
      float s=0.f;
#pragma unroll
      for(int k=0;k<8;k++) s += redW[row*64 + ((seg*8+k) ^ ((row*9)&63))];
      s += __shfl_xor(s,1,64);
      s += __shfl_xor(s,2,64);
      s += __shfl_xor(s,4,64);
      if(seg==0) dh3S[w*128 + (row&1)*64 + jc*4 + (row>>1)] = s;
    }
    __syncthreads();
  }
  // restage W3 (Wbuf writes) overlapped with Wbuf-independent angular reductions + ds1
  for(int i4=t;i4<1024;i4+=256){
    int i=i4*4; const float4 v=*(const float4*)&W3[i];
    float* dst=&Wbuf[((i>>6)*65)+(i&63)];
    dst[0]=v.x; dst[1]=v.y; dst[2]=v.z; dst[3]=v.w;
  }
  float dux[2], duy[2], duz[2];
#pragma unroll
  for(int i=0;i<2;i++){
    int le=w*2+i; int rc=rcvS[le];
    size_t eg=e0+le;
    float vx=cvec[eg*3+0], vy=cvec[eg*3+1], vz=cvec[eg*3+2];
    float invr=1.f/cr[eg];
    float ux=vx*invr, uy=vy*invr, uz=vz*invr;
    const float s3=1.7320508f, s5=2.23606798f, s15=3.87298335f;
    float dm[9], d_[9];
#pragma unroll
    for(int l=0;l<LL;l++){
      dm[l]=dagg[(size_t)l*LSTR+(size_t)rc*FF+f]*INV_AVG;
      d_[l]=dm[l]*sv[i]*tw[i][l];
    }
    float duxp = s3*d_[1] + s15*(uy*d_[4] + uz*d_[7] + ux*d_[8]);
    float duyp = s3*d_[2] + s15*(ux*d_[4] + uz*d_[5] - uy*d_[8]);
    float duzp = s3*d_[3] + s15*(uy*d_[5] + ux*d_[7]) + 3.f*s5*uz*d_[6];
    dux[i]=wred(duxp); duy[i]=wred(duyp); duz[i]=wred(duzp);
    if(LAYER==2){
      float A=0.f;
#pragma unroll
      for(int l=0;l<LL;l++) A += dm[l]*shs[le*LL+l]*tw[i][l];
      atomicAdd(&ds1[(size_t)sndS[le]*FF+f], A);
    }
  } // dm, tw, dtw dead — registers freed for the chain
  __syncthreads();   // Wbuf = W3 ready; all waves past redW scribbling
  // chain: dz3 -> dh2 -> dz2 (W3); restage W2 -> dh1 -> dz1
#pragma unroll
  for(int i=0;i<2;i++){
    int le=w*2+i;
    float dh3 = dh3S[w*128 + i*64 + f];
    float sg3 = 1.f/(1.f+__expf(-z3r[i]));
    hQ[le*FF+f] = dh3*sg3*(1.f + z3r[i]*(1.f-sg3));   // dz3, wave-private row
  }
  float dz2r[2];
#pragma unroll
  for(int i=0;i<2;i++){
    int le=w*2+i; float dh2=0.f;
#pragma unroll
    for(int c4=0;c4<16;c4++){
      const float4 dv=*(const float4*)&hQ[le*FF+c4*4];
      dh2 += dv.x*Wbuf[f*65+c4*4+0];
      dh2 += dv.y*Wbuf[f*65+c4*4+1];
      dh2 += dv.z*Wbuf[f*65+c4*4+2];
      dh2 += dv.w*Wbuf[f*65+c4*4+3];
    }
    float sg2=1.f/(1.f+__expf(-z2r[i]));
    dz2r[i]=dh2*sg2*(1.f + z2r[i]*(1.f-sg2));
  }
  __syncthreads();
  for(int i4=t;i4<1024;i4+=256){
    int i=i4*4; const float4 v=*(const float4*)&W2[i];
    float* dst=&Wbuf[((i>>6)*65)+(i&63)];
    dst[0]=v.x; dst[1]=v.y; dst[2]=v.z; dst[3]=v.w;
  }
  __syncthreads();
#pragma unroll
  for(int i=0;i<2;i++){ int le=w*2+i; hQ[le*FF+f]=dz2r[i]; }
#pragma unroll
  for(int i=0;i<2;i++){
    int le=w*2+i;
    float dh1=0.f;
#pragma unroll
    for(int c4=0;c4<16;c4++){
      const float4 dv=*(const float4*)&hQ[le*FF+c4*4];
      dh1 += dv.x*Wbuf[f*65+c4*4+0];
      dh1 += dv.y*Wbuf[f*65+c4*4+1];
      dh1 += dv.z*Wbuf[f*65+c4*4+2];
      dh1 += dv.w*Wbuf[f*65+c4*4+3];
    }
    float sg1=1.f/(1.f+__expf(-z1r[i]));
    float dz1=dh1*sg1*(1.f + z1r[i]*(1.f-sg1));
    size_t eg=e0+le;
    float r=cr[eg];
    float invr=1.f/r;
    float vx=cvec[eg*3+0], vy=cvec[eg*3+1], vz=cvec[eg*3+2];
    float ux=vx*invr, uy=vy*invr, uz=vz*invr;
    float xr=r*(1.f/RMAXF);
    float x2=xr*xr, x4=x2*x2, x5=x4*xr, x6=x5*xr, x7=x6*xr;
    float env=1.f-28.f*x6+48.f*x7-21.f*x7*xr;
    float envd=(-168.f*x5+336.f*x6-168.f*x7)*(1.f/RMAXF);
    const float CB=0.632455532f;
    float B=0.f;
#pragma unroll
    for(int b=0;b<NBB;b++){
      float a=(b+1)*(PI_F/RMAXF);
      float ar=a*r;
      float sn_=__sinf(ar), cs_=__cosf(ar);
      float bess=CB*sn_*invr;
      float bessd=(ar<1e-2f)?(-CB*a*a*a*r*(1.f/3.f)):(CB*(a*cs_-sn_*invr)*invr);
      B += W1s[b*FF+f]*(bessd*env + bess*envd);
    }
    float dr = wred(dz1*B);
    float udd=ux*dux[i]+uy*duy[i]+uz*duz[i];
    float dvx=dr*ux+(dux[i]-ux*udd)*invr;
    float dvy=dr*uy+(duy[i]-uy*udd)*invr;
    float dvz=dr*uz+(duz[i]-uz*udd)*invr;
    if(f==0){
      if(LAYER==2){
        dvec[eg*3+0]=dvx; dvec[eg*3+1]=dvy; dvec[eg*3+2]=dvz;
      } else {
        int sn=sndS[le], rc=rcvS[le];
        float tx=dvec[eg*3+0]+dvx, ty=dvec[eg*3+1]+dvy, tz=dvec[eg*3+2]+dvz;
        atomicAdd(&dpos[rc*3+0],tx); atomicAdd(&dpos[rc*3+1],ty); atomicAdd(&dpos[rc*3+2],tz);
        atomicAdd(&dpos[sn*3+0],-tx); atomicAdd(&dpos[sn*3+1],-ty); atomicAdd(&dpos[sn*3+2],-tz);
      }
    }
  }
}

__global__ __launch_bounds__(256) void k_forces(const float* __restrict__ dpos,
                                                float* __restrict__ forces){
  int i = blockIdx.x*256+threadIdx.x;
  if(i < NNODES*3) forces[i] = -dpos[i];
}

extern "C" void kernel_launch(void* const* d_in, const int* in_sizes, int n_in,
                              void* d_out, int out_size, void* d_ws, size_t ws_size,
                              hipStream_t stream){
  (void)in_sizes; (void)n_in; (void)out_size; (void)ws_size;
  const float* pos    = (const float*)d_in[0];
  const float* attrs  = (const float*)d_in[1];
  const float* shifts = (const float*)d_in[2];
  const float* ae     = (const float*)d_in[3];
  const float* Wemb   = (const float*)d_in[4];
  const float* R1W1   = (const float*)d_in[5];
  const float* R1W2   = (const float*)d_in[6];
  const float* R1W3   = (const float*)d_in[7];
  const float* R1W4   = (const float*)d_in[8];
  const float* R2W1   = (const float*)d_in[9];
  const float* R2W2   = (const float*)d_in[10];
  const float* R2W3   = (const float*)d_in[11];
  const float* R2W4   = (const float*)d_in[12];
  const float* Wlin1  = (const float*)d_in[13];
  const float* Wsc1   = (const float*)d_in[14];
  const float* Wpr1   = (const float*)d_in[15];
  const float* wrd1   = (const float*)d_in[16];
  const float* Wlin2  = (const float*)d_in[17];
  const float* Wsc2   = (const float*)d_in[18];
  const float* Wpr2   = (const float*)d_in[19];
  const float* Wr1    = (const float*)d_in[20];
  const float* wr2    = (const float*)d_in[21];
  const int*   eidx   = (const int*)d_in[22];
  const int*   batch  = (const int*)d_in[23];

  float* out = (float*)d_out;
  float* ws  = (float*)d_ws;
  float* totE   = out;          // 32
  float* nodeE  = out + 32;     // 10000
  float* forces = out + 10032;  // 30000
  float* nfeats = out + 40032;  // 10000*1152

  float* h0   = ws + O_H0;
  float* s1   = ws + O_S1;
  float* agg1 = ws + O_AGG1;
  float* agg2 = ws + O_AGG2;
  float* f1   = ws + O_F1;
  float* f2   = ws + O_F2;
  float* c1   = ws + O_C1;
  float* c2   = ws + O_C2;
  float* ds1  = ws + O_DS1;
  float* csh  = ws + O_CSH;
  float* cef  = ws + O_CEF;
  float* crr  = ws + O_CR;
  float* cvec = ws + O_CVEC;
  float* dvec = ws + O_DVEC;
  float* dpos = ws + O_DPOS;
  int* csnd = (int*)(ws + O_CSND);
  int* crcv = (int*)(ws + O_CRCV);
  int* hist = (int*)(ws + O_HIST);
  int* curs = (int*)(ws + O_CURS);
  int* cnt  = (int*)(ws + O_CNT);
  float* w4p1 = ws + O_W4P1;
  float* w4p2 = ws + O_W4P2;
  float* dagg2 = agg1;
  float* dagg1 = agg2;

  hipMemsetAsync(totE, 0, 32*sizeof(float), stream);
  hipMemsetAsync(agg1, 0, (size_t)2*5760000*sizeof(float), stream);
  hipMemsetAsync(dpos, 0, 30000*sizeof(float), stream);
  hipMemsetAsync(hist, 0, NNODES*sizeof(int), stream);

  dim3 gLin(313,9);

  k_w4prep<<<384,256,0,stream>>>(R1W4, R2W4, w4p1, w4p2);
  k_embed<<<2500,256,0,stream>>>(attrs, Wemb, ae, batch, h0, totE, nodeE);
  k_count<<<1000,256,0,stream>>>(pos, shifts, eidx, hist);
  k_scan<<<1,1024,0,stream>>>(hist, curs, cnt);
  k_scatter<<<1000,256,0,stream>>>(pos, shifts, eidx, curs, csh, cef, crr, cvec, csnd, crcv);
  k_pad<<<1,32,0,stream>>>(csh, cef, crr, cvec, csnd, crcv, cnt);

  k_edge_fwd<<<ECAP/32,256,0,stream>>>(csh,cef,csnd,crcv,cnt, h0,
                                       R1W1,R1W2,R1W3,w4p1, agg1);
  k_lin2<<<gLin,256,0,stream>>>(agg1, Wlin1, h0, Wsc1, f1);
  k_prod<1><<<1250,256,0,stream>>>(f1, batch, Wpr1, wrd1, nullptr, nullptr,
                                   c1, s1, nfeats, nodeE, totE);
  k_edge_fwd<<<ECAP/32,256,0,stream>>>(csh,cef,csnd,crcv,cnt, s1,
                                       R2W1,R2W2,R2W3,w4p2, agg2);
  k_lin2<<<gLin,256,0,stream>>>(agg2, Wlin2, s1, Wsc2, f2);
  k_prod<2><<<1250,256,0,stream>>>(f2, batch, Wpr2, nullptr, Wr1, wr2,
                                   c2, nullptr, nfeats, nodeE, totE);

  k_node_bwd<2><<<313,256,0,stream>>>(f2, c2, Wpr2, Wsc2, Wr1, wr2,
                                      nullptr, nullptr, Wlin2, ds1, dagg2);
  k_edge_bwd<2><<<ECAP/8,256,0,stream>>>(csh,cef,crr,cvec,csnd,crcv,cnt, s1,
                                         R2W1,R2W2,R2W3,R2W4, dagg2,
                                         ds1, dvec, nullptr);
  k_node_bwd<1><<<313,256,0,stream>>>(f1, c1, Wpr1, nullptr, nullptr, nullptr,
                                      wrd1, ds1, Wlin1, nullptr, dagg1);
  k_edge_bwd<1><<<ECAP/8,256,0,stream>>>(csh,cef,crr,cvec,csnd,crcv,cnt, h0,
                                         R1W1,R1W2,R1W3,R1W4, dagg1,
                                         nullptr, dvec, dpos);
  k_forces<<<118,256,0,stream>>>(dpos, forces);
}

// Round 10
// 2309.954 us; speedup vs baseline: 1.0325x; 1.0325x over previous
//
#include <hip/hip_runtime.h>
#include <cstddef>

#define NNODES 10000
#define NEDGES 256000
#define NGRAPH 32
#define NELEM  10
#define FF     64
#define LL     9
#define NBB    8
#define HIDN   16
#define RMAXF  5.0f
#define INV_AVG 0.0390625f   /* 1/25.6 exact */
#define PI_F   3.14159265358979f
#define ECAP   98304         /* compact-edge capacity; expected active ~74.7k */
#define LSTR   640000        /* l-major stride for agg/dagg/feats: [l][n][f] */

// ---------------- workspace layout (float elements), ~120.9 MB ----------------
constexpr size_t O_H0    = 0;           // 640000
constexpr size_t O_S1    = 640000;      // 640000
constexpr size_t O_AGG1  = 1280000;     // 5760000 (fwd agg1; reused as d_agg2 in bwd)
constexpr size_t O_AGG2  = 7040000;     // 5760000 (fwd agg2; reused as d_agg1 in bwd)
constexpr size_t O_F1    = 12800000;    // 5760000 feats1 [l][n][g]
constexpr size_t O_F2    = 18560000;    // 5760000 feats2 [l][n][g]
constexpr size_t O_C1    = 24320000;    // 640000
constexpr size_t O_C2    = 24960000;    // 640000
constexpr size_t O_DS1   = 25600000;    // 640000
constexpr size_t O_CSH   = 27520000;    // ECAP*9
constexpr size_t O_CEF   = 28404736;    // ECAP*8
constexpr size_t O_CR    = 29191168;    // ECAP
constexpr size_t O_CVEC  = 29289472;    // ECAP*3
constexpr size_t O_DVEC  = 29584384;    // ECAP*3
constexpr size_t O_DPOS  = 29879296;    // 30000
constexpr size_t O_CSND  = 29909296;    // ECAP ints
constexpr size_t O_CRCV  = 30007600;    // ECAP ints
constexpr size_t O_HIST  = 30105904;    // 10000 ints
constexpr size_t O_CURS  = 30115904;    // 10001 ints
constexpr size_t O_CNT   = 30125905;    // 2 ints
constexpr size_t O_W4P1  = 30125920;    // 49152 (W4 padded: [j][f][12], fwd only)
constexpr size_t O_W4P2  = 30175072;    // 49152

__device__ __forceinline__ float siluf(float z){
  return z*(1.f/(1.f+__expf(-z)));
}
__device__ __forceinline__ float wred(float v){
#pragma unroll
  for(int o=32;o>0;o>>=1) v += __shfl_xor(v,o,64);
  return v;
}

// ---------------- W4 pre-pad: W4P[j*768 + f*12 + l] = W4[j*576 + f*9 + l] ----------------
__global__ __launch_bounds__(256) void k_w4prep(
    const float* __restrict__ W4a, const float* __restrict__ W4b,
    float* __restrict__ W4Pa, float* __restrict__ W4Pb){
  int o = blockIdx.x*256 + threadIdx.x;          // 0..98303
  int which = (o >= 49152) ? 1 : 0;
  int oo = o - which*49152;
  int l = oo % 12;
  int fj = oo / 12;
  int ff = fj & 63;
  int j  = fj >> 6;
  const float* src = which ? W4b : W4a;
  float v = (l < 9) ? src[j*576 + ff*9 + l] : 0.f;
  (which ? W4Pb : W4Pa)[oo] = v;
}

// ---------------- node embedding + e0 ----------------
__global__ __launch_bounds__(256) void k_embed(
    const float* __restrict__ attrs, const float* __restrict__ Wemb,
    const float* __restrict__ ae, const int* __restrict__ batch,
    float* __restrict__ h0, float* __restrict__ totE, float* __restrict__ nodeE){
  int t = blockIdx.x*256 + threadIdx.x;
  int n = t >> 6, f = t & 63;
  float acc = 0.f;
#pragma unroll
  for(int k=0;k<NELEM;k++) acc += attrs[n*NELEM+k]*Wemb[k*FF+f];
  h0[(size_t)n*FF+f] = acc;
  if(f==0){
    float e0 = 0.f;
#pragma unroll
    for(int k=0;k<NELEM;k++) e0 += attrs[n*NELEM+k]*ae[k];
    nodeE[n] = e0;
    atomicAdd(&totE[batch[n]], e0);
  }
}

// ---------------- edge sort: count / scan / scatter / pad ----------------
__global__ __launch_bounds__(256) void k_count(
    const float* __restrict__ pos, const float* __restrict__ shifts,
    const int* __restrict__ eidx, int* __restrict__ hist){
  int e = blockIdx.x*256 + threadIdx.x;
  int sn = eidx[e], rc = eidx[NEDGES + e];
  float vx = pos[rc*3+0]-pos[sn*3+0]+shifts[(size_t)e*3+0];
  float vy = pos[rc*3+1]-pos[sn*3+1]+shifts[(size_t)e*3+1];
  float vz = pos[rc*3+2]-pos[sn*3+2]+shifts[(size_t)e*3+2];
  float r2 = vx*vx+vy*vy+vz*vz+1e-12f;
  if(r2 < RMAXF*RMAXF) atomicAdd(&hist[rc], 1);
}

__global__ __launch_bounds__(1024) void k_scan(
    const int* __restrict__ hist, int* __restrict__ cursor, int* __restrict__ cnt){
  __shared__ int buf[1024];
  __shared__ int carryS;
  int t = threadIdx.x;
  if(t==0) carryS = 0;
  __syncthreads();
  for(int c=0;c<10;c++){
    int i = c*1024 + t;
    int v = (i<NNODES)? hist[i] : 0;
    buf[t]=v;
    __syncthreads();
    for(int off=1; off<1024; off<<=1){
      int x = (t>=off)? buf[t-off] : 0;
      __syncthreads();
      buf[t] += x;
      __syncthreads();
    }
    int incl = buf[t];
    int base = carryS;
    if(i<NNODES) cursor[i] = base + incl - v;
    __syncthreads();
    if(t==1023) carryS += buf[1023];
    __syncthreads();
  }
  if(t==0){
    int n = carryS;
    cnt[0] = n;
    cnt[1] = (n+31)&~31;
  }
}

__global__ __launch_bounds__(256) void k_scatter(
    const float* __restrict__ pos, const float* __restrict__ shifts, const int* __restrict__ eidx,
    int* __restrict__ cursor,
    float* __restrict__ csh, float* __restrict__ cef, float* __restrict__ cr,
    float* __restrict__ cvec, int* __restrict__ csnd, int* __restrict__ crcv){
  int e = blockIdx.x*256 + threadIdx.x;
  int sn = eidx[e], rc = eidx[NEDGES + e];
  float vx = pos[rc*3+0]-pos[sn*3+0]+shifts[(size_t)e*3+0];
  float vy = pos[rc*3+1]-pos[sn*3+1]+shifts[(size_t)e*3+1];
  float vz = pos[rc*3+2]-pos[sn*3+2]+shifts[(size_t)e*3+2];
  float r2 = vx*vx+vy*vy+vz*vz+1e-12f;
  if(r2 >= RMAXF*RMAXF) return;
  float r = sqrtf(r2);
  int i = atomicAdd(&cursor[rc], 1);
  csnd[i]=sn; crcv[i]=rc; cr[i]=r;
  cvec[(size_t)i*3+0]=vx; cvec[(size_t)i*3+1]=vy; cvec[(size_t)i*3+2]=vz;
  float inv = 1.f/r, x=vx*inv, y=vy*inv, z=vz*inv;
  const float s3=1.7320508f, s5=2.23606798f, s15=3.87298335f;
  float* sh = csh + (size_t)i*LL;
  sh[0]=1.f; sh[1]=s3*x; sh[2]=s3*y; sh[3]=s3*z; sh[4]=s15*x*y; sh[5]=s15*y*z;
  sh[6]=0.5f*s5*(3.f*z*z-1.f); sh[7]=s15*x*z; sh[8]=0.5f*s15*(x*x-y*y);
  float xr = r*(1.f/RMAXF);
  float x2=xr*xr, x4=x2*x2, x6=x4*x2, x7=x6*xr, x8=x7*xr;
  float env = 1.f - 28.f*x6 + 48.f*x7 - 21.f*x8;
  const float CB = 0.632455532f;
#pragma unroll
  for(int b=0;b<NBB;b++){
    float a = (b+1)*(PI_F/RMAXF);
    cef[(size_t)i*NBB+b] = CB*sinf(a*r)*inv*env;
  }
}

__global__ void k_pad(float* csh, float* cef, float* cr, float* cvec,
                      int* csnd, int* crcv, const int* cnt){
  int n = cnt[0];
  int nr = cnt[1];
  int i = n + threadIdx.x;
  if(i < nr){
    csnd[i]=0; crcv[i]=NNODES-1; cr[i]=1.f;
    cvec[(size_t)i*3+0]=0.f; cvec[(size_t)i*3+1]=0.f; cvec[(size_t)i*3+2]=1.f;
    for(int l=0;l<LL;l++) csh[(size_t)i*LL+l]=0.f;
    for(int b=0;b<NBB;b++) cef[(size_t)i*NBB+b]=0.f;
  }
}

// ---------------- fused edge forward: MLP -> tw (W4 from global W4P) -> segmented reduce ----
__global__ __launch_bounds__(256,2) void k_edge_fwd(
    const float* __restrict__ csh, const float* __restrict__ cef,
    const int* __restrict__ csnd, const int* __restrict__ crcv, const int* __restrict__ cnt,
    const float* __restrict__ src,
    const float* __restrict__ W1, const float* __restrict__ W2,
    const float* __restrict__ W3, const float* __restrict__ W4P,
    float* __restrict__ agg){
  const int cnt32 = cnt[1];
  if((int)(blockIdx.x*32) >= cnt32) return;
  __shared__ float W1s[NBB*FF];
  __shared__ float Wbuf[FF*65];        // W2 -> W3
  __shared__ float hA[32*FF], hB[32*FF];
  __shared__ float shs[32*LL], efs[32*NBB];
  __shared__ int   sndS[32], rcvS[32];
  const int t = threadIdx.x;
  const size_t e0 = (size_t)blockIdx.x*32;
  for(int i=t;i<NBB*FF;i+=256) W1s[i]=W1[i];
  for(int i4=t;i4<1024;i4+=256){
    int i=i4*4; const float4 v=*(const float4*)&W2[i];
    float* dst=&Wbuf[((i>>6)*65)+(i&63)];
    dst[0]=v.x; dst[1]=v.y; dst[2]=v.z; dst[3]=v.w;
  }
  for(int i=t;i<32*LL;i+=256) shs[i]=csh[e0*LL+i];
  for(int i=t;i<32*NBB;i+=256) efs[i]=cef[e0*NBB+i];
  if(t<32){ sndS[t]=csnd[e0+t]; rcvS[t]=crcv[e0+t]; }
  __syncthreads();
  const int w=t>>6, f=t&63;
  // L1: h1 -> hA   (rows wave-private)
#pragma unroll
  for(int i=0;i<8;i++){
    int e=w*8+i; float z=0.f;
#pragma unroll
    for(int b=0;b<NBB;b++) z += efs[e*NBB+b]*W1s[b*FF+f];
    hA[e*FF+f]=siluf(z);
  }
  // L2: h2 -> hB  (Wbuf = W2)
#pragma unroll
  for(int i=0;i<8;i++){
    int e=w*8+i; float z=0.f;
#pragma unroll
    for(int j4=0;j4<16;j4++){
      const float4 hv=*(const float4*)&hA[e*FF+j4*4];
      z += hv.x*Wbuf[(j4*4+0)*65+f];
      z += hv.y*Wbuf[(j4*4+1)*65+f];
      z += hv.z*Wbuf[(j4*4+2)*65+f];
      z += hv.w*Wbuf[(j4*4+3)*65+f];
    }
    hB[e*FF+f]=siluf(z);
  }
  __syncthreads();
  for(int i4=t;i4<1024;i4+=256){
    int i=i4*4; const float4 v=*(const float4*)&W3[i];
    float* dst=&Wbuf[((i>>6)*65)+(i&63)];
    dst[0]=v.x; dst[1]=v.y; dst[2]=v.z; dst[3]=v.w;
  }
  __syncthreads();
  // L3: h3 -> hA  (Wbuf = W3)
#pragma unroll
  for(int i=0;i<8;i++){
    int e=w*8+i; float z=0.f;
#pragma unroll
    for(int j4=0;j4<16;j4++){
      const float4 hv=*(const float4*)&hB[e*FF+j4*4];
      z += hv.x*Wbuf[(j4*4+0)*65+f];
      z += hv.y*Wbuf[(j4*4+1)*65+f];
      z += hv.z*Wbuf[(j4*4+2)*65+f];
      z += hv.w*Wbuf[(j4*4+3)*65+f];
    }
    hA[e*FF+f]=siluf(z);
  }
  // W4 pass: direct from global W4P [j][f][12] — 8 edges/wave amortize the stream
  float tw[8][9];
#pragma unroll
  for(int i=0;i<8;i++)
#pragma unroll
    for(int l=0;l<LL;l++) tw[i][l]=0.f;
  for(int jc=0;jc<16;jc++){
    float4 h4[8];
#pragma unroll
    for(int i=0;i<8;i++) h4[i]=*(const float4*)&hA[(w*8+i)*FF + jc*4];
#pragma unroll
    for(int j4=0;j4<4;j4++){
      const float* wp = W4P + (size_t)(jc*4+j4)*768 + f*12;
      const float4 wa=*(const float4*)wp;
      const float4 wb=*(const float4*)(wp+4);
      const float  w8=wp[8];
#pragma unroll
      for(int i=0;i<8;i++){
        const float h3=(j4==0)?h4[i].x:(j4==1)?h4[i].y:(j4==2)?h4[i].z:h4[i].w;
        tw[i][0]+=h3*wa.x; tw[i][1]+=h3*wa.y; tw[i][2]+=h3*wa.z; tw[i][3]+=h3*wa.w;
        tw[i][4]+=h3*wb.x; tw[i][5]+=h3*wb.y; tw[i][6]+=h3*wb.z; tw[i][7]+=h3*wb.w;
        tw[i][8]+=h3*w8;
      }
    }
  }
  // epilogue: per-l LDS run reduction into l-major agg [l][n][f]; msgL = hB (h2 dead)
  float sv[8];
#pragma unroll
  for(int i=0;i<8;i++) sv[i] = src[(size_t)sndS[w*8+i]*FF + f];
  const bool leftStraddle  = (e0>0) && (crcv[e0-1] == rcvS[0]);
  const bool rightStraddle = ((int)(e0+32) < cnt32) && (crcv[e0+32] == rcvS[31]);
  float* msgL = hB;
#pragma unroll
  for(int l=0;l<LL;l++){
#pragma unroll
    for(int i=0;i<8;i++){
      int e=w*8+i;
      msgL[e*FF+f] = sv[i]*shs[e*LL+l]*tw[i][l]*INV_AVG;
    }
    __syncthreads();
#pragma unroll
    for(int s0=0;s0<8;s0++){
      int s = w*8+s0;
      int rc = rcvS[s];
      bool head = (s==0) || (rcvS[s-1]!=rc);
      if(head){
        int L=1;
        while(s+L<32 && rcvS[s+L]==rc) L++;
        float sum=0.f;
        for(int k=0;k<L;k++) sum += msgL[(s+k)*FF+f];
        bool atom = (s==0 && leftStraddle) || (s+L==32 && rightStraddle);
        float* ap = &agg[(size_t)l*LSTR + (size_t)rc*FF + f];
        if(atom) atomicAdd(ap, sum); else *ap = sum;
      }
    }
    __syncthreads();
  }
}

// ---------------- k_lin2: feats[l][n][g] = sum_f agg[l][n][f]*Wlin[l][f][g] (+sc at l=0) ----
__global__ __launch_bounds__(256,2) void k_lin2(
    const float* __restrict__ agg, const float* __restrict__ Wlin,
    const float* __restrict__ src, const float* __restrict__ Wsc,
    float* __restrict__ feats){
  const int l    = blockIdx.y;
  const int base = blockIdx.x*32;
  __shared__ float Wl[FF*65];
  __shared__ float aS[32*FF];
  const int t=threadIdx.x, w=t>>6, g=t&63;
  for(int i=t;i<FF*FF;i+=256) Wl[(i>>6)*65+(i&63)] = Wlin[(size_t)l*FF*FF+i];
#pragma unroll
  for(int j=0;j<8;j++){
    int idx=t+j*256;
    int n = base + (idx>>6);
    aS[idx] = (n<NNODES)? agg[(size_t)l*LSTR + (size_t)n*FF + (idx&63)] : 0.f;
  }
  __syncthreads();
  float acc[8];
#pragma unroll
  for(int i=0;i<8;i++) acc[i]=0.f;
#pragma unroll 4
  for(int f4=0;f4<16;f4++){
    float w0=Wl[(f4*4+0)*65+g], w1=Wl[(f4*4+1)*65+g],
          w2=Wl[(f4*4+2)*65+g], w3=Wl[(f4*4+3)*65+g];
#pragma unroll
    for(int i=0;i<8;i++){
      const float4 v = *(const float4*)&aS[(w*8+i)*FF + f4*4];
      acc[i] += w0*v.x+w1*v.y+w2*v.z+w3*v.w;
    }
  }
  if(l==0){
    __syncthreads();
    for(int i=t;i<FF*FF;i+=256) Wl[(i>>6)*65+(i&63)] = Wsc[i];
#pragma unroll
    for(int j=0;j<8;j++){
      int idx=t+j*256;
      int n = base + (idx>>6);
      aS[idx] = (n<NNODES)? src[(size_t)n*FF + (idx&63)] : 0.f;
    }
    __syncthreads();
#pragma unroll 4
    for(int f4=0;f4<16;f4++){
      float w0=Wl[(f4*4+0)*65+g], w1=Wl[(f4*4+1)*65+g],
            w2=Wl[(f4*4+2)*65+g], w3=Wl[(f4*4+3)*65+g];
#pragma unroll
      for(int i=0;i<8;i++){
        const float4 v = *(const float4*)&aS[(w*8+i)*FF + f4*4];
        acc[i] += w0*v.x+w1*v.y+w2*v.z+w3*v.w;
      }
    }
  }
#pragma unroll
  for(int i=0;i<8;i++){
    int n = base + w*8 + i;
    if(n<NNODES) feats[(size_t)l*LSTR + (size_t)n*FF + g] = acc[i];
  }
}

// ---------------- k_prod: inv, c, h, readout energies ----------------
template<int LAYER>
__global__ __launch_bounds__(256,2) void k_prod(
    const float* __restrict__ feats, const int* __restrict__ batch,
    const float* __restrict__ Wpr,
    const float* __restrict__ wread, const float* __restrict__ Wr1, const float* __restrict__ wr2,
    float* __restrict__ cbuf, float* __restrict__ s1out,
    float* __restrict__ nfeats, float* __restrict__ nodeE, float* __restrict__ totE){
  __shared__ float Wprs[FF*65];
  __shared__ float Wr1s[FF*HIDN];
  __shared__ float ivS[4][FF];
  const int t=threadIdx.x, w=t>>6, g=t&63;
  for(int i=t;i<FF*FF;i+=256) Wprs[(i>>6)*65+(i&63)]=Wpr[i];
  if(LAYER==2) for(int i=t;i<FF*HIDN;i+=256) Wr1s[i]=Wr1[i];
  __syncthreads();
  for(int k=0;k<2;k++){
    int n = blockIdx.x*8 + k*4 + w;
    if(n>=NNODES) continue;   // wave-uniform; no block barriers below
    float fr[9]; float iv=0.f;
#pragma unroll
    for(int l=0;l<LL;l++){ fr[l]=feats[(size_t)l*LSTR + (size_t)n*FF + g]; iv+=fr[l]*fr[l]; }
    ivS[w][g]=iv;
    float c=1.f;
#pragma unroll
    for(int gg=0;gg<FF;gg++) c += ivS[w][gg]*Wprs[gg*65+g];
    cbuf[(size_t)n*FF+g]=c;
    float* nf = nfeats + (size_t)n*(2*FF*LL) + (LAYER==2?FF*LL:0) + g*LL;
#pragma unroll
    for(int l=0;l<LL;l++) nf[l]=fr[l]*c;
    float s0 = fr[0]*c;
    float epart;
    if(LAYER==1){
      s1out[(size_t)n*FF+g]=s0;
      epart = s0*wread[g];
    } else {
      ivS[w][g]=s0;
      epart=0.f;
      if(g<HIDN){
        float tt=0.f;
#pragma unroll
        for(int gg=0;gg<FF;gg++) tt += ivS[w][gg]*Wr1s[gg*HIDN+g];
        epart = siluf(tt)*wr2[g];
      }
    }
    float es = wred(epart);
    if(g==0){ nodeE[n]+=es; atomicAdd(&totE[batch[n]], es); }
  }
}

// ---------------- k_node_bwd: fused bwd_prep + lin_bwd (dinv/dh0c stay in LDS) -------------
template<int LAYER>
__global__ __launch_bounds__(256,2) void k_node_bwd(
    const float* __restrict__ feats, const float* __restrict__ cbuf,
    const float* __restrict__ Wpr, const float* __restrict__ Wsc,
    const float* __restrict__ Wr1, const float* __restrict__ wr2,
    const float* __restrict__ wread, const float* __restrict__ ds1in,
    const float* __restrict__ Wlin,
    float* __restrict__ ds1out, float* __restrict__ dagg){
  __shared__ float WbufA[FF*65];                      // Wpr (phase A) -> Wlin[l] (phase B)
  __shared__ float WbufB[(LAYER==2)?FF*65:1];         // Wsc (L2 only)
  __shared__ float poolA[2048];                       // Wr1s[0..1023]+Wr1T[1024..2047] -> fS
  __shared__ float dinvS[32*FF];
  __shared__ float dh0cS[32*FF];
  __shared__ float rowS[4][FF];
  __shared__ float dtS[4][HIDN];
  const int t=threadIdx.x, w=t>>6, g=t&63;
  const int base = blockIdx.x*32;
  for(int i=t;i<FF*FF;i+=256) WbufA[(i>>6)*65+(i&63)]=Wpr[i];
  if(LAYER==2){
    for(int i=t;i<FF*FF;i+=256) WbufB[(i>>6)*65+(i&63)]=Wsc[i];
    for(int i=t;i<FF*HIDN;i+=256){
      poolA[i]=Wr1[i];                                // Wr1s [f][h]
      poolA[1024 + (i&15)*FF + (i>>4)]=Wr1[i];        // Wr1T [h][f]
    }
  }
  __syncthreads();
  // ---- phase A: dinv, dh0c (to LDS), ds1out (L2, global) ----
  for(int k=0;k<8;k++){
    int ni = k*4+w;
    int n  = base + ni;
    if(n>=NNODES) continue;                           // wave-uniform
    float f0 = feats[(size_t)n*FF+g];                 // l=0 plane
    float c  = cbuf[(size_t)n*FF+g];
    float dh0;
    if(LAYER==2){
      rowS[w][g] = f0*c;                              // s2 row
      if(g<HIDN){
        float tt=0.f;
#pragma unroll
        for(int gg=0;gg<FF;gg++) tt += rowS[w][gg]*poolA[gg*HIDN+g];
        float sg = 1.f/(1.f+__expf(-tt));
        dtS[w][g] = sg*(1.f + tt*(1.f-sg))*wr2[g];
      }
      dh0=0.f;
#pragma unroll
      for(int h=0;h<HIDN;h++) dh0 += dtS[w][h]*poolA[1024 + h*FF + g];
    } else {
      dh0 = wread[g] + ds1in[(size_t)n*FF+g];
    }
    rowS[w][g] = dh0*f0;                              // dc
    float dinv=0.f;
#pragma unroll
    for(int gg=0;gg<FF;gg++) dinv += rowS[w][gg]*WbufA[g*65+gg];
    dinvS[ni*FF+g]=dinv;
    dh0cS[ni*FF+g]=dh0*c;
    if(LAYER==2){
      rowS[w][g] = 2.f*dinv*f0 + dh0*c;               // df0
      float ds=0.f;
#pragma unroll
      for(int gg=0;gg<FF;gg++) ds += rowS[w][gg]*WbufB[g*65+gg];
      ds1out[(size_t)n*FF+g]=ds;
    }
  }
  __syncthreads();
  // ---- phase B: per-l GEMM  dagg[l][n][f] = sum_g df[n][g]*Wlin[l][f][g] ----
  float* fS = poolA;                                  // 2048 floats, reused
  for(int l=0;l<LL;l++){
    for(int i=t;i<FF*FF;i+=256) WbufA[(i>>6)*65+(i&63)]=Wlin[(size_t)l*FF*FF+i];
#pragma unroll
    for(int j=0;j<8;j++){
      int idx=t+j*256;
      int n = base + (idx>>6);
      float v=0.f;
      if(n<NNODES){
        float ft = feats[(size_t)l*LSTR+(size_t)n*FF+(idx&63)];
        v = 2.f*dinvS[idx]*ft;
        if(l==0) v += dh0cS[idx];
      }
      fS[idx]=v;
    }
    __syncthreads();
    float acc[8];
#pragma unroll
    for(int i=0;i<8;i++) acc[i]=0.f;
#pragma unroll 4
    for(int f4=0;f4<16;f4++){
      float w0=WbufA[g*65+f4*4+0], w1=WbufA[g*65+f4*4+1],
            w2=WbufA[g*65+f4*4+2], w3=WbufA[g*65+f4*4+3];
#pragma unroll
      for(int i=0;i<8;i++){
        const float4 v = *(const float4*)&fS[(w*8+i)*FF + f4*4];
        acc[i] += w0*v.x+w1*v.y+w2*v.z+w3*v.w;
      }
    }
#pragma unroll
    for(int i=0;i<8;i++){
      int n = base + w*8 + i;
      if(n<NNODES) dagg[(size_t)l*LSTR + (size_t)n*FF + g] = acc[i];
    }
    __syncthreads();
  }
}

// ---------------- fused edge backward: 2 edges/wave (r8 schedule) + 4KB redS diet -----------
// W4c[2] double-buffer, 1 barrier/chunk (r8's proven pipeline). redW: wave0->hP, wave1->hQ
// (h1/h2 dead after L3; barrier added post-L3), waves2/3 -> dedicated redS2. LDS ~50.2KB
// -> 3 blocks/CU fit. No waves-per-EU hint: compiler free (observed need ~120 VGPR).
template<int LAYER>
__global__ __launch_bounds__(256) void k_edge_bwd(
    const float* __restrict__ csh, const float* __restrict__ cef,
    const float* __restrict__ cr, const float* __restrict__ cvec,
    const int* __restrict__ csnd, const int* __restrict__ crcv, const int* __restrict__ cnt,
    const float* __restrict__ src,
    const float* __restrict__ W1, const float* __restrict__ W2,
    const float* __restrict__ W3, const float* __restrict__ W4,
    const float* __restrict__ dagg,
    float* __restrict__ ds1,
    float* __restrict__ dvec,
    float* __restrict__ dpos){
  if((int)(blockIdx.x*8) >= cnt[1]) return;
  __shared__ float W1s[NBB*FF];        // 2KB
  __shared__ float Wbuf[FF*65];        // 16.6KB: W2 -> W3 (held through W4+chain) -> W2
  __shared__ float hP[8*FF];           // h1; redW wave0 during W4 pass
  __shared__ float hQ[8*FF];           // h2; redW wave1; dz3; dz2
  __shared__ float hR[8*FF];           // h3
  __shared__ float shs[8*LL], efs[8*NBB];
  __shared__ float redS2[2*512];       // 4KB redW for waves 2,3
  __shared__ float dh3S[4*2*64];       // 2KB per-wave dh3 [w][i][j]
  __shared__ float W4c[2][4*576];      // 18.4KB double-buffered W4 chunk [j4][f][9]
  __shared__ int sndS[8], rcvS[8];
  const int t=threadIdx.x, w=t>>6, f=t&63;
  const size_t e0=(size_t)blockIdx.x*8;
  const float4* W4v=(const float4*)W4;
  for(int i=t;i<NBB*FF;i+=256) W1s[i]=W1[i];
  for(int i4=t;i4<1024;i4+=256){
    int i=i4*4; const float4 v=*(const float4*)&W2[i];
    float* dst=&Wbuf[((i>>6)*65)+(i&63)];
    dst[0]=v.x; dst[1]=v.y; dst[2]=v.z; dst[3]=v.w;
  }
  if(t<8*LL)  shs[t]=csh[e0*LL+t];
  if(t<8*NBB) efs[t]=cef[e0*NBB+t];
  if(t<8){ sndS[t]=csnd[e0+t]; rcvS[t]=crcv[e0+t]; }
  __syncthreads();
  // early long-latency loads
  float sv[2], dtw[2][9];
  float z1r[2], z2r[2], z3r[2];
#pragma unroll
  for(int i=0;i<2;i++) sv[i]=src[(size_t)sndS[w*2+i]*FF+f];
#pragma unroll
  for(int i=0;i<2;i++){
    int le=w*2+i; int rc=rcvS[le];
#pragma unroll
    for(int l=0;l<LL;l++){
      float dm0=dagg[(size_t)l*LSTR+(size_t)rc*FF+f]*INV_AVG;
      dtw[i][l]=dm0*sv[i]*shs[le*LL+l];
    }
  }
  // MLP forward recompute; z kept in registers for the chain
#pragma unroll
  for(int i=0;i<2;i++){
    int le=w*2+i; float z=0.f;
#pragma unroll
    for(int b=0;b<NBB;b++) z += efs[le*NBB+b]*W1s[b*FF+f];
    z1r[i]=z; hP[le*FF+f]=siluf(z);
  }
#pragma unroll
  for(int i=0;i<2;i++){
    int le=w*2+i; float z=0.f;
#pragma unroll
    for(int j4=0;j4<16;j4++){
      const float4 hv=*(const float4*)&hP[le*FF+j4*4];
      z += hv.x*Wbuf[(j4*4+0)*65+f];
      z += hv.y*Wbuf[(j4*4+1)*65+f];
      z += hv.z*Wbuf[(j4*4+2)*65+f];
      z += hv.w*Wbuf[(j4*4+3)*65+f];
    }
    z2r[i]=z; hQ[le*FF+f]=siluf(z);
  }
  __syncthreads();
  for(int i4=t;i4<1024;i4+=256){
    int i=i4*4; const float4 v=*(const float4*)&W3[i];
    float* dst=&Wbuf[((i>>6)*65)+(i&63)];
    dst[0]=v.x; dst[1]=v.y; dst[2]=v.z; dst[3]=v.w;
  }
  // prologue: stage W4 chunk 0 (covered by the barrier below)
  for(int d4=t; d4<576; d4+=256) ((float4*)W4c[0])[d4] = W4v[d4];
  __syncthreads();
#pragma unroll
  for(int i=0;i<2;i++){
    int le=w*2+i; float z=0.f;
#pragma unroll
    for(int j4=0;j4<16;j4++){
      const float4 hv=*(const float4*)&hQ[le*FF+j4*4];
      z += hv.x*Wbuf[(j4*4+0)*65+f];
      z += hv.y*Wbuf[(j4*4+1)*65+f];
      z += hv.z*Wbuf[(j4*4+2)*65+f];
      z += hv.w*Wbuf[(j4*4+3)*65+f];
    }
    z3r[i]=z; hR[le*FF+f]=siluf(z);
  }
  __syncthreads();   // h1/h2 (hP/hQ) now dead everywhere -> safe as redW scratch
  // W4 pass: stage chunk jc+1 while computing chunk jc; one barrier per chunk
  float tw[2][9];
#pragma unroll
  for(int i=0;i<2;i++)
#pragma unroll
    for(int l=0;l<LL;l++) tw[i][l]=0.f;
  float* redW = (w==0)? hP : (w==1)? hQ : &redS2[(w-2)*512];
  const int row=f>>3, seg=f&7;
  int cur=0;
  for(int jc=0;jc<16;jc++){
    if(jc<15){
      float* dst=(float*)W4c[cur^1];
      for(int d4=t; d4<576; d4+=256) ((float4*)dst)[d4] = W4v[(jc+1)*576 + d4];
    }
    const float* Wc = W4c[cur];
    float4 h3v[2];
    h3v[0]=*(const float4*)&hR[(w*2+0)*FF + jc*4];
    h3v[1]=*(const float4*)&hR[(w*2+1)*FF + jc*4];
    float p[4][2];
#pragma unroll
    for(int j4=0;j4<4;j4++){
      const float* wp = Wc + j4*576 + f*9;
      const float w0=wp[0], w1=wp[1], w2=wp[2], w3=wp[3], w4_=wp[4],
                  w5=wp[5], w6=wp[6], w7=wp[7], w8=wp[8];
#pragma unroll
      for(int i=0;i<2;i++){
        const float h3=(j4==0)?h3v[i].x:(j4==1)?h3v[i].y:(j4==2)?h3v[i].z:h3v[i].w;
        tw[i][0]+=h3*w0; tw[i][1]+=h3*w1; tw[i][2]+=h3*w2; tw[i][3]+=h3*w3;
        tw[i][4]+=h3*w4_; tw[i][5]+=h3*w5; tw[i][6]+=h3*w6; tw[i][7]+=h3*w7;
        tw[i][8]+=h3*w8;
        float pp=0.f;
        pp+=dtw[i][0]*w0; pp+=dtw[i][1]*w1; pp+=dtw[i][2]*w2; pp+=dtw[i][3]*w3;
        pp+=dtw[i][4]*w4_; pp+=dtw[i][5]*w5; pp+=dtw[i][6]*w6; pp+=dtw[i][7]*w7;
        pp+=dtw[i][8]*w8;
        p[j4][i]=pp;
      }
    }
    // per-wave transpose-reduce (8 rows, XOR swizzle (r*9)&63 — verified round 2)
#pragma unroll
    for(int j4=0;j4<4;j4++)
#pragma unroll
      for(int i=0;i<2;i++){
        int r=j4*2+i;
        redW[r*64 + (f ^ ((r*9)&63))] = p[j4][i];
      }
    {
      float s=0.f;
#pragma unroll
      for(int k=0;k<8;k++) s += redW[row*64 + ((seg*8+k) ^ ((row*9)&63))];
      s += __shfl_xor(s,1,64);
      s += __shfl_xor(s,2,64);
      s += __shfl_xor(s,4,64);
      if(seg==0) dh3S[w*128 + (row&1)*64 + jc*4 + (row>>1)] = s;
    }
    __syncthreads();
    cur ^= 1;
  }
  // angular reductions + ds1 (dm reloaded; dagg L2-hot); Wbuf still holds W3
  float dux[2], duy[2], duz[2];
#pragma unroll
  for(int i=0;i<2;i++){
    int le=w*2+i; int rc=rcvS[le];
    size_t eg=e0+le;
    float vx=cvec[eg*3+0], vy=cvec[eg*3+1], vz=cvec[eg*3+2];
    float invr=1.f/cr[eg];
    float ux=vx*invr, uy=vy*invr, uz=vz*invr;
    const float s3=1.7320508f, s5=2.23606798f, s15=3.87298335f;
    float dm[9], d_[9];
#pragma unroll
    for(int l=0;l<LL;l++){
      dm[l]=dagg[(size_t)l*LSTR+(size_t)rc*FF+f]*INV_AVG;
      d_[l]=dm[l]*sv[i]*tw[i][l];
    }
    float duxp = s3*d_[1] + s15*(uy*d_[4] + uz*d_[7] + ux*d_[8]);
    float duyp = s3*d_[2] + s15*(ux*d_[4] + uz*d_[5] - uy*d_[8]);
    float duzp = s3*d_[3] + s15*(uy*d_[5] + ux*d_[7]) + 3.f*s5*uz*d_[6];
    dux[i]=wred(duxp); duy[i]=wred(duyp); duz[i]=wred(duzp);
    if(LAYER==2){
      float A=0.f;
#pragma unroll
      for(int l=0;l<LL;l++) A += dm[l]*shs[le*LL+l]*tw[i][l];
      atomicAdd(&ds1[(size_t)sndS[le]*FF+f], A);
    }
  } // dm, tw, dtw dead — registers freed for the chain
  __syncthreads();   // all waves past redW scribbling before hQ reused as dz3
  // chain: Wbuf = W3 (untouched) -> dz3 -> dh2 -> dz2; restage W2 -> dh1 -> dz1
#pragma unroll
  for(int i=0;i<2;i++){
    int le=w*2+i;
    float dh3 = dh3S[w*128 + i*64 + f];
    float sg3 = 1.f/(1.f+__expf(-z3r[i]));
    hQ[le*FF+f] = dh3*sg3*(1.f + z3r[i]*(1.f-sg3));   // dz3, wave-private row
  }
  float dz2r[2];
#pragma unroll
  for(int i=0;i<2;i++){
    int le=w*2+i; float dh2=0.f;
#pragma unroll
    for(int c4=0;c4<16;c4++){
      const float4 dv=*(const float4*)&hQ[le*FF+c4*4];
      dh2 += dv.x*Wbuf[f*65+c4*4+0];
      dh2 += dv.y*Wbuf[f*65+c4*4+1];
      dh2 += dv.z*Wbuf[f*65+c4*4+2];
      dh2 += dv.w*Wbuf[f*65+c4*4+3];
    }
    float sg2=1.f/(1.f+__expf(-z2r[i]));
    dz2r[i]=dh2*sg2*(1.f + z2r[i]*(1.f-sg2));
  }
  __syncthreads();
  for(int i4=t;i4<1024;i4+=256){
    int i=i4*4; const float4 v=*(const float4*)&W2[i];
    float* dst=&Wbuf[((i>>6)*65)+(i&63)];
    dst[0]=v.x; dst[1]=v.y; dst[2]=v.z; dst[3]=v.w;
  }
  __syncthreads();
#pragma unroll
  for(int i=0;i<2;i++){ int le=w*2+i; hQ[le*FF+f]=dz2r[i]; }
#pragma unroll
  for(int i=0;i<2;i++){
    int le=w*2+i;
    float dh1=0.f;
#pragma unroll
    for(int c4=0;c4<16;c4++){
      const float4 dv=*(const float4*)&hQ[le*FF+c4*4];
      dh1 += dv.x*Wbuf[f*65+c4*4+0];
      dh1 += dv.y*Wbuf[f*65+c4*4+1];
      dh1 += dv.z*Wbuf[f*65+c4*4+2];
      dh1 += dv.w*Wbuf[f*65+c4*4+3];
    }
    float sg1=1.f/(1.f+__expf(-z1r[i]));
    float dz1=dh1*sg1*(1.f + z1r[i]*(1.f-sg1));
    size_t eg=e0+le;
    float r=cr[eg];
    float invr=1.f/r;
    float vx=cvec[eg*3+0], vy=cvec[eg*3+1], vz=cvec[eg*3+2];
    float ux=vx*invr, uy=vy*invr, uz=vz*invr;
    float xr=r*(1.f/RMAXF);
    float x2=xr*xr, x4=x2*x2, x5=x4*xr, x6=x5*xr, x7=x6*xr;
    float env=1.f-28.f*x6+48.f*x7-21.f*x7*xr;
    float envd=(-168.f*x5+336.f*x6-168.f*x7)*(1.f/RMAXF);
    const float CB=0.632455532f;
    float B=0.f;
#pragma unroll
    for(int b=0;b<NBB;b++){
      float a=(b+1)*(PI_F/RMAXF);
      float ar=a*r;
      float sn_=__sinf(ar), cs_=__cosf(ar);
      float bess=CB*sn_*invr;
      float bessd=(ar<1e-2f)?(-CB*a*a*a*r*(1.f/3.f)):(CB*(a*cs_-sn_*invr)*invr);
      B += W1s[b*FF+f]*(bessd*env + bess*envd);
    }
    float dr = wred(dz1*B);
    float udd=ux*dux[i]+uy*duy[i]+uz*duz[i];
    float dvx=dr*ux+(dux[i]-ux*udd)*invr;
    float dvy=dr*uy+(duy[i]-uy*udd)*invr;
    float dvz=dr*uz+(duz[i]-uz*udd)*invr;
    if(f==0){
      if(LAYER==2){
        dvec[eg*3+0]=dvx; dvec[eg*3+1]=dvy; dvec[eg*3+2]=dvz;
      } else {
        int sn=sndS[le], rc=rcvS[le];
        float tx=dvec[eg*3+0]+dvx, ty=dvec[eg*3+1]+dvy, tz=dvec[eg*3+2]+dvz;
        atomicAdd(&dpos[rc*3+0],tx); atomicAdd(&dpos[rc*3+1],ty); atomicAdd(&dpos[rc*3+2],tz);
        atomicAdd(&dpos[sn*3+0],-tx); atomicAdd(&dpos[sn*3+1],-ty); atomicAdd(&dpos[sn*3+2],-tz);
      }
    }
  }
}

__global__ __launch_bounds__(256) void k_forces(const float* __restrict__ dpos,
                                                float* __restrict__ forces){
  int i = blockIdx.x*256+threadIdx.x;
  if(i < NNODES*3) forces[i] = -dpos[i];
}

extern "C" void kernel_launch(void* const* d_in, const int* in_sizes, int n_in,
                              void* d_out, int out_size, void* d_ws, size_t ws_size,
                              hipStream_t stream){
  (void)in_sizes; (void)n_in; (void)out_size; (void)ws_size;
  const float* pos    = (const float*)d_in[0];
  const float* attrs  = (const float*)d_in[1];
  const float* shifts = (const float*)d_in[2];
  const float* ae     = (const float*)d_in[3];
  const float* Wemb   = (const float*)d_in[4];
  const float* R1W1   = (const float*)d_in[5];
  const float* R1W2   = (const float*)d_in[6];
  const float* R1W3   = (const float*)d_in[7];
  const float* R1W4   = (const float*)d_in[8];
  const float* R2W1   = (const float*)d_in[9];
  const float* R2W2   = (const float*)d_in[10];
  const float* R2W3   = (const float*)d_in[11];
  const float* R2W4   = (const float*)d_in[12];
  const float* Wlin1  = (const float*)d_in[13];
  const float* Wsc1   = (const float*)d_in[14];
  const float* Wpr1   = (const float*)d_in[15];
  const float* wrd1   = (const float*)d_in[16];
  const float* Wlin2  = (const float*)d_in[17];
  const float* Wsc2   = (const float*)d_in[18];
  const float* Wpr2   = (const float*)d_in[19];
  const float* Wr1    = (const float*)d_in[20];
  const float* wr2    = (const float*)d_in[21];
  const int*   eidx   = (const int*)d_in[22];
  const int*   batch  = (const int*)d_in[23];

  float* out = (float*)d_out;
  float* ws  = (float*)d_ws;
  float* totE   = out;          // 32
  float* nodeE  = out + 32;     // 10000
  float* forces = out + 10032;  // 30000
  float* nfeats = out + 40032;  // 10000*1152

  float* h0   = ws + O_H0;
  float* s1   = ws + O_S1;
  float* agg1 = ws + O_AGG1;
  float* agg2 = ws + O_AGG2;
  float* f1   = ws + O_F1;
  float* f2   = ws + O_F2;
  float* c1   = ws + O_C1;
  float* c2   = ws + O_C2;
  float* ds1  = ws + O_DS1;
  float* csh  = ws + O_CSH;
  float* cef  = ws + O_CEF;
  float* crr  = ws + O_CR;
  float* cvec = ws + O_CVEC;
  float* dvec = ws + O_DVEC;
  float* dpos = ws + O_DPOS;
  int* csnd = (int*)(ws + O_CSND);
  int* crcv = (int*)(ws + O_CRCV);
  int* hist = (int*)(ws + O_HIST);
  int* curs = (int*)(ws + O_CURS);
  int* cnt  = (int*)(ws + O_CNT);
  float* w4p1 = ws + O_W4P1;
  float* w4p2 = ws + O_W4P2;
  float* dagg2 = agg1;
  float* dagg1 = agg2;

  hipMemsetAsync(totE, 0, 32*sizeof(float), stream);
  hipMemsetAsync(agg1, 0, (size_t)2*5760000*sizeof(float), stream);
  hipMemsetAsync(dpos, 0, 30000*sizeof(float), stream);
  hipMemsetAsync(hist, 0, NNODES*sizeof(int), stream);

  dim3 gLin(313,9);

  k_w4prep<<<384,256,0,stream>>>(R1W4, R2W4, w4p1, w4p2);
  k_embed<<<2500,256,0,stream>>>(attrs, Wemb, ae, batch, h0, totE, nodeE);
  k_count<<<1000,256,0,stream>>>(pos, shifts, eidx, hist);
  k_scan<<<1,1024,0,stream>>>(hist, curs, cnt);
  k_scatter<<<1000,256,0,stream>>>(pos, shifts, eidx, curs, csh, cef, crr, cvec, csnd, crcv);
  k_pad<<<1,32,0,stream>>>(csh, cef, crr, cvec, csnd, crcv, cnt);

  k_edge_fwd<<<ECAP/32,256,0,stream>>>(csh,cef,csnd,crcv,cnt, h0,
                                       R1W1,R1W2,R1W3,w4p1, agg1);
  k_lin2<<<gLin,256,0,stream>>>(agg1, Wlin1, h0, Wsc1, f1);
  k_prod<1><<<1250,256,0,stream>>>(f1, batch, Wpr1, wrd1, nullptr, nullptr,
                                   c1, s1, nfeats, nodeE, totE);
  k_edge_fwd<<<ECAP/32,256,0,stream>>>(csh,cef,csnd,crcv,cnt, s1,
                                       R2W1,R2W2,R2W3,w4p2, agg2);
  k_lin2<<<gLin,256,0,stream>>>(agg2, Wlin2, s1, Wsc2, f2);
  k_prod<2><<<1250,256,0,stream>>>(f2, batch, Wpr2, nullptr, Wr1, wr2,
                                   c2, nullptr, nfeats, nodeE, totE);

  k_node_bwd<2><<<313,256,0,stream>>>(f2, c2, Wpr2, Wsc2, Wr1, wr2,
                                      nullptr, nullptr, Wlin2, ds1, dagg2);
  k_edge_bwd<2><<<ECAP/8,256,0,stream>>>(csh,cef,crr,cvec,csnd,crcv,cnt, s1,
                                         R2W1,R2W2,R2W3,R2W4, dagg2,
                                         ds1, dvec, nullptr);
  k_node_bwd<1><<<313,256,0,stream>>>(f1, c1, Wpr1, nullptr, nullptr, nullptr,
                                      wrd1, ds1, Wlin1, nullptr, dagg1);
  k_edge_bwd<1><<<ECAP/8,256,0,stream>>>(csh,cef,crr,cvec,csnd,crcv,cnt, h0,
                                         R1W1,R1W2,R1W3,R1W4, dagg1,
                                         nullptr, dvec, dpos);
  k_forces<<<118,256,0,stream>>>(dpos, forces);
}